// Round 1
// baseline (434.473 us; speedup 1.0000x reference)
//
#include <hip/hip_runtime.h>
#include <float.h>

#define SPLITS 16
#define CHAIN_UNROLL 8

// ws layout:
//   [0 .. B*8)        : unsigned long long packed[B]  (atomic argmax slots, zeroed by memset)
//   [B*8 .. B*8+B*4)  : unsigned int count[B]         (arrival counters, zeroed by memset)

__global__ __launch_bounds__(256) void fused_kernel(
    const float* __restrict__ draft_probs,
    const float* __restrict__ target_probs,
    const float* __restrict__ uniform_probs,
    const int*   __restrict__ draft_ids,
    const int*   __restrict__ cu,
    const int*   __restrict__ bonus,
    int*         __restrict__ out,
    unsigned long long* __restrict__ packed,
    unsigned int* __restrict__ count,
    int B, int V, int NT, int L)
{
    const int b   = blockIdx.x;
    const int s   = blockIdx.y;
    const int tid = threadIdx.x;

    const int start  = (b == 0) ? 0 : cu[b - 1];
    const int nd     = cu[b] - start;
    const int nchain = (nd < L) ? nd : L;
    const int nc8    = (nchain < CHAIN_UNROLL) ? nchain : CHAIN_UNROLL;

    // ---- redundant per-block chain (all threads hit identical addresses ->
    //      coalesced broadcast loads; 16 sibling blocks share L2 lines) ----
    float pi = 1.0f, U = 1.0f;
    int last = -1;
    int mydid = -1;

    int   did[CHAIN_UNROLL];
    float tp[CHAIN_UNROLL], dp[CHAIN_UNROLL], uu[CHAIN_UNROLL];

    // batch 1: independent id + uniform loads
#pragma unroll
    for (int i = 0; i < CHAIN_UNROLL; ++i) {
        did[i] = (i < nc8) ? draft_ids[start + i]     : -1;
        uu[i]  = (i < nc8) ? uniform_probs[start + i] : 1.0f;
    }
    // batch 2: dependent prob gathers (independent of each other)
#pragma unroll
    for (int i = 0; i < CHAIN_UNROLL; ++i) {
        if (i < nc8) {
            const size_t off = (size_t)(start + i) * (size_t)V + (size_t)did[i];
            tp[i] = target_probs[off];
            dp[i] = draft_probs[off];
        } else { tp[i] = 0.0f; dp[i] = 0.0f; }
    }
    // recurrence (register-only, statically indexed)
#pragma unroll
    for (int i = 0; i < CHAIN_UNROLL; ++i) {
        if (i < nc8) {
            const bool  ok = dp[i] > 0.0f;
            const float r  = ok ? (tp[i] / dp[i]) : 1.0f;   // IEEE div, matches ref
            pi = fminf(pi * r, 1.0f);
            U  = U * uu[i];
            if (ok && pi >= U) last = i;
            if (tid == i) mydid = did[i];
        }
    }
    // generic tail for L > CHAIN_UNROLL (never taken in this problem)
    for (int i = CHAIN_UNROLL; i < nchain; ++i) {
        const int t = start + i;
        const int d = draft_ids[t];
        const size_t off = (size_t)t * (size_t)V + (size_t)d;
        const float tpv = target_probs[off];
        const float dpv = draft_probs[off];
        const bool  ok  = dpv > 0.0f;
        const float r   = ok ? (tpv / dpv) : 1.0f;
        pi = fminf(pi * r, 1.0f);
        U *= uniform_probs[t];
        if (ok && pi >= U) last = i;
        if (tid == i) mydid = d;
    }

    const bool rejected = (nd > 0) && (last != nd - 1);

    // ---- output row: block s==0 only. When rejected, column last+1 is left
    //      to the finalizer block (no same-address cross-block store pair). ----
    if (s == 0 && tid <= L) {
        int val = (tid <= last) ? mydid : -1;
        if (!rejected && tid == nd) val = bonus[b];
        if (!(rejected && tid == last + 1))
            out[(size_t)b * (L + 1) + tid] = val;
    }

    if (!rejected) return;   // all 16 blocks exit; row fully written by s==0

    // ---- split argmax over target_probs row rr ----
    int rr = start + last + 1;
    rr = rr < 0 ? 0 : (rr > NT - 1 ? NT - 1 : rr);
    const float* rowbase = target_probs + (size_t)rr * (size_t)V;

    const int n4     = V >> 2;
    const int chunk4 = (n4 + SPLITS - 1) / SPLITS;
    const int lo4    = s * chunk4;
    const int hi4    = (lo4 + chunk4 < n4) ? lo4 + chunk4 : n4;

    float bestv = -FLT_MAX;
    int   besti = 0x7fffffff;
    const float4* rowp = (const float4*)rowbase;
    for (int j = lo4 + tid; j < hi4; j += 256) {
        const float4 v = rowp[j];
        const int base = j << 2;
        if (v.x > bestv) { bestv = v.x; besti = base;     }
        if (v.y > bestv) { bestv = v.y; besti = base + 1; }
        if (v.z > bestv) { bestv = v.z; besti = base + 2; }
        if (v.w > bestv) { bestv = v.w; besti = base + 3; }
    }
    if (s == SPLITS - 1) {                       // scalar tail if V % 4 != 0
        for (int j = (n4 << 2) + tid; j < V; j += 256) {
            const float v = rowbase[j];
            if (v > bestv) { bestv = v; besti = j; }
        }
    }

    __shared__ float sv[256];
    __shared__ int   si[256];
    sv[tid] = bestv;
    si[tid] = besti;
    __syncthreads();
    for (int w = 128; w > 0; w >>= 1) {
        if (tid < w) {
            const float ov = sv[tid + w];
            const int   oi = si[tid + w];
            if (ov > sv[tid] || (ov == sv[tid] && oi < si[tid])) {
                sv[tid] = ov;
                si[tid] = oi;
            }
        }
        __syncthreads();
    }

    if (tid == 0) {
        if (sv[0] > -FLT_MAX) {
            // pack: high 32 = float bits (nonneg => order-monotone),
            // low 32 = ~index => among equal values, smaller index wins
            const unsigned int fbits = __float_as_uint(sv[0]);
            const unsigned long long p =
                ((unsigned long long)fbits << 32) |
                (unsigned long long)(0xFFFFFFFFu - (unsigned int)si[0]);
            atomicMax(&packed[b], p);
        }
        __threadfence();                                  // release our max
        const unsigned int old = atomicAdd(&count[b], 1u);
        if (old == SPLITS - 1) {                          // last arrival finalizes
            const unsigned long long p = atomicMax(&packed[b], 0ull); // atomic read
            const int idx = (int)(0xFFFFFFFFu - (unsigned int)(p & 0xFFFFFFFFull));
            out[(size_t)b * (L + 1) + (last + 1)] = idx;
        }
    }
}

extern "C" void kernel_launch(void* const* d_in, const int* in_sizes, int n_in,
                              void* d_out, int out_size, void* d_ws, size_t ws_size,
                              hipStream_t stream) {
    const float* draft_probs   = (const float*)d_in[0];
    const float* target_probs  = (const float*)d_in[1];
    const float* uniform_probs = (const float*)d_in[2];
    const int*   draft_ids     = (const int*)d_in[3];
    const int*   cu            = (const int*)d_in[4];
    const int*   bonus         = (const int*)d_in[5];
    int*         out           = (int*)d_out;

    const int NT = in_sizes[2];
    const int V  = in_sizes[0] / NT;
    const int B  = in_sizes[4];
    const int L  = out_size / B - 1;

    unsigned long long* packed = (unsigned long long*)d_ws;
    unsigned int* count = (unsigned int*)((char*)d_ws + (size_t)B * 8);

    // zero packed[B] + count[B] (1.5 KB) — graph-capturable memset node
    hipMemsetAsync(d_ws, 0, (size_t)B * 12, stream);

    dim3 grid(B, SPLITS);
    fused_kernel<<<grid, 256, 0, stream>>>(
        draft_probs, target_probs, uniform_probs, draft_ids, cu, bonus,
        out, packed, count, B, V, NT, L);
}

// Round 3
// 423.541 us; speedup vs baseline: 1.0258x; 1.0258x over previous
//
#include <hip/hip_runtime.h>
#include <float.h>

#define SPLITS 16

// ws layout:
//   [0 .. B*8)            : unsigned long long packed[B]   (atomic argmax slots)
//   [B*8 .. +B*4)         : int flag[B]      (1 = rejected, needs argmax)
//   [.. +B*4)             : int recrow[B]
//   [.. +B*4)             : int writecol[B]
//   [.. +B*4)             : unsigned int count[B]  (arrival counters)

__global__ void chain_kernel(
    const float* __restrict__ draft_probs,
    const float* __restrict__ target_probs,
    const float* __restrict__ uniform_probs,
    const int*   __restrict__ draft_ids,
    const int*   __restrict__ cu,
    const int*   __restrict__ bonus,
    int*         __restrict__ out,
    unsigned long long* __restrict__ packed,
    int* __restrict__ flag, int* __restrict__ recrow, int* __restrict__ writecol,
    unsigned int* __restrict__ count,
    int B, int V, int NT, int L)
{
    const int b = blockIdx.x * blockDim.x + threadIdx.x;
    if (b >= B) return;

    const int start = (b == 0) ? 0 : cu[b - 1];
    const int nd    = cu[b] - start;
    const int nchain = (nd < L) ? nd : L;

    float pi = 1.0f, U = 1.0f;
    int last = -1;
    int* row = out + (size_t)b * (L + 1);

    for (int i = 0; i < nchain; ++i) {
        const int t   = start + i;
        const int did = draft_ids[t];
        row[i] = did;                       // provisional; masked below
        const size_t off = (size_t)t * (size_t)V + (size_t)did;
        const float tp = target_probs[off];
        const float dp = draft_probs[off];
        const float uu = uniform_probs[t];
        const bool ok = dp > 0.0f;
        const float r = ok ? (tp / dp) : 1.0f;   // IEEE div, matches np
        pi = fminf(pi * r, 1.0f);
        U  = U * uu;
        if (ok && pi >= U) last = i;
    }
    // mask out non-accepted positions
    for (int i = last + 1; i <= L; ++i) row[i] = -1;

    const bool rejected = (nd > 0) && (last != nd - 1);
    if (!rejected) {
        row[nd] = bonus[b];
    }
    int rr = start + last + 1;
    rr = rr < 0 ? 0 : (rr > NT - 1 ? NT - 1 : rr);

    flag[b]     = rejected ? 1 : 0;
    recrow[b]   = rr;
    writecol[b] = last + 1;
    packed[b]   = 0ull;   // init atomic slot (probs > 0 beat this)
    count[b]    = 0u;
}

__global__ __launch_bounds__(256) void argmax_kernel(
    const float* __restrict__ target_probs,
    int* __restrict__ out,
    unsigned long long* __restrict__ packed,
    const int* __restrict__ flag, const int* __restrict__ recrow,
    const int* __restrict__ writecol,
    unsigned int* __restrict__ count,
    int V, int L)
{
    const int b = blockIdx.x;
    const int s = blockIdx.y;
    if (!flag[b]) return;                 // cheap early-out (kernel-boundary ordered)

    const int tid = threadIdx.x;
    const float* rowbase = target_probs + (size_t)recrow[b] * (size_t)V;
    const int n4 = V >> 2;
    const int chunk4 = (n4 + SPLITS - 1) / SPLITS;
    const int lo4 = s * chunk4;
    const int hi4 = (lo4 + chunk4 < n4) ? lo4 + chunk4 : n4;

    float bestv = -FLT_MAX;
    int   besti = 0x7fffffff;
    const float4* rowp = (const float4*)rowbase;
    for (int j = lo4 + tid; j < hi4; j += 256) {
        const float4 v = rowp[j];
        const int base = j << 2;
        if (v.x > bestv) { bestv = v.x; besti = base;     }
        if (v.y > bestv) { bestv = v.y; besti = base + 1; }
        if (v.z > bestv) { bestv = v.z; besti = base + 2; }
        if (v.w > bestv) { bestv = v.w; besti = base + 3; }
    }
    if (s == SPLITS - 1) {                // scalar tail if V % 4 != 0
        for (int j = (n4 << 2) + tid; j < V; j += 256) {
            const float v = rowbase[j];
            if (v > bestv) { bestv = v; besti = j; }
        }
    }

    __shared__ float sv[256];
    __shared__ int   si[256];
    sv[tid] = bestv;
    si[tid] = besti;
    __syncthreads();
    for (int w = 128; w > 0; w >>= 1) {
        if (tid < w) {
            const float ov = sv[tid + w];
            const int   oi = si[tid + w];
            if (ov > sv[tid] || (ov == sv[tid] && oi < si[tid])) {
                sv[tid] = ov;
                si[tid] = oi;
            }
        }
        __syncthreads();
    }

    if (tid == 0) {
        if (sv[0] > -FLT_MAX) {
            // pack: high 32 = float bits (nonneg => order-monotone),
            // low 32 = ~index => among equal values, smaller index wins
            const unsigned int fbits = __float_as_uint(sv[0]);
            const unsigned long long p =
                ((unsigned long long)fbits << 32) |
                (unsigned long long)(0xFFFFFFFFu - (unsigned int)si[0]);
            atomicMax(&packed[b], p);
        }
        __threadfence();                              // release our contribution
        const unsigned int old = atomicAdd(&count[b], 1u);
        if (old == SPLITS - 1) {                      // last arrival finalizes
            const unsigned long long p = atomicMax(&packed[b], 0ull); // atomic read
            const int idx = (int)(0xFFFFFFFFu - (unsigned int)(p & 0xFFFFFFFFull));
            out[(size_t)b * (L + 1) + writecol[b]] = idx;
        }
    }
}

extern "C" void kernel_launch(void* const* d_in, const int* in_sizes, int n_in,
                              void* d_out, int out_size, void* d_ws, size_t ws_size,
                              hipStream_t stream) {
    const float* draft_probs   = (const float*)d_in[0];
    const float* target_probs  = (const float*)d_in[1];
    const float* uniform_probs = (const float*)d_in[2];
    const int*   draft_ids     = (const int*)d_in[3];
    const int*   cu            = (const int*)d_in[4];
    const int*   bonus         = (const int*)d_in[5];
    int*         out           = (int*)d_out;

    const int NT = in_sizes[2];
    const int V  = in_sizes[0] / NT;
    const int B  = in_sizes[4];
    const int L  = out_size / B - 1;

    unsigned long long* packed = (unsigned long long*)d_ws;
    char* base = (char*)d_ws + (size_t)B * 8;
    int* flag     = (int*)(base);
    int* recrow   = (int*)(base + (size_t)B * 4);
    int* writecol = (int*)(base + (size_t)B * 8);
    unsigned int* count = (unsigned int*)(base + (size_t)B * 12);

    const int bthreads = 256;
    const int bblocks  = (B + bthreads - 1) / bthreads;

    chain_kernel<<<bblocks, bthreads, 0, stream>>>(
        draft_probs, target_probs, uniform_probs, draft_ids, cu, bonus,
        out, packed, flag, recrow, writecol, count, B, V, NT, L);

    dim3 grid(B, SPLITS);
    argmax_kernel<<<grid, 256, 0, stream>>>(
        target_probs, out, packed, flag, recrow, writecol, count, V, L);
}

// Round 4
// 408.051 us; speedup vs baseline: 1.0648x; 1.0380x over previous
//
#include <hip/hip_runtime.h>
#include <hip/hip_bf16.h>
#include <float.h>

#define SPLITS 16

// ws layout:
//   [0 .. B*8)            : unsigned long long packed[B]   (atomic argmax slots)
//   [B*8 .. B*8+B*4)      : int flag[B]      (1 = rejected, needs argmax)
//   [.. +B*4)             : int recrow[B]
//   [.. +B*4)             : int writecol[B]

__global__ void chain_kernel(
    const float* __restrict__ draft_probs,
    const float* __restrict__ target_probs,
    const float* __restrict__ uniform_probs,
    const int*   __restrict__ draft_ids,
    const int*   __restrict__ cu,
    const int*   __restrict__ bonus,
    int*         __restrict__ out,
    unsigned long long* __restrict__ packed,
    int* __restrict__ flag, int* __restrict__ recrow, int* __restrict__ writecol,
    int B, int V, int NT, int L)
{
    const int b = blockIdx.x * blockDim.x + threadIdx.x;
    if (b >= B) return;

    const int start = (b == 0) ? 0 : cu[b - 1];
    const int nd    = cu[b] - start;
    const int nchain = (nd < L) ? nd : L;

    float pi = 1.0f, U = 1.0f;
    int last = -1;
    int* row = out + (size_t)b * (L + 1);

    for (int i = 0; i < nchain; ++i) {
        const int t   = start + i;
        const int did = draft_ids[t];
        row[i] = did;                       // provisional; masked below
        const size_t off = (size_t)t * (size_t)V + (size_t)did;
        const float tp = target_probs[off];
        const float dp = draft_probs[off];
        const float uu = uniform_probs[t];
        const bool ok = dp > 0.0f;
        const float r = ok ? (tp / dp) : 1.0f;   // IEEE div, matches np
        pi = fminf(pi * r, 1.0f);
        U  = U * uu;
        if (ok && pi >= U) last = i;
    }
    // mask out non-accepted positions
    for (int i = last + 1; i <= L; ++i) row[i] = -1;

    const bool rejected = (nd > 0) && (last != nd - 1);
    if (!rejected) {
        row[nd] = bonus[b];
    }
    int rr = start + last + 1;
    rr = rr < 0 ? 0 : (rr > NT - 1 ? NT - 1 : rr);

    flag[b]     = rejected ? 1 : 0;
    recrow[b]   = rr;
    writecol[b] = last + 1;
    packed[b]   = 0ull;   // init atomic slot (probs > 0 beat this)
}

__global__ __launch_bounds__(256) void argmax_partial_kernel(
    const float* __restrict__ target_probs,
    const unsigned long long* __restrict__ /*unused*/,
    unsigned long long* __restrict__ packed,
    const int* __restrict__ flag, const int* __restrict__ recrow,
    int V)
{
    const int b = blockIdx.x;
    const int s = blockIdx.y;
    if (!flag[b]) return;

    const int tid = threadIdx.x;
    const float* rowbase = target_probs + (size_t)recrow[b] * (size_t)V;
    const int n4 = V >> 2;
    const int chunk4 = (n4 + SPLITS - 1) / SPLITS;
    const int lo4 = s * chunk4;
    const int hi4 = (lo4 + chunk4 < n4) ? lo4 + chunk4 : n4;

    float bestv = -FLT_MAX;
    int   besti = 0x7fffffff;
    const float4* rowp = (const float4*)rowbase;
    for (int j = lo4 + tid; j < hi4; j += 256) {
        const float4 v = rowp[j];
        const int base = j << 2;
        if (v.x > bestv) { bestv = v.x; besti = base;     }
        if (v.y > bestv) { bestv = v.y; besti = base + 1; }
        if (v.z > bestv) { bestv = v.z; besti = base + 2; }
        if (v.w > bestv) { bestv = v.w; besti = base + 3; }
    }
    if (s == SPLITS - 1) {
        for (int j = (n4 << 2) + tid; j < V; j += 256) {
            const float v = rowbase[j];
            if (v > bestv) { bestv = v; besti = j; }
        }
    }

    __shared__ float sv[256];
    __shared__ int   si[256];
    sv[tid] = bestv;
    si[tid] = besti;
    __syncthreads();
    for (int w = 128; w > 0; w >>= 1) {
        if (tid < w) {
            const float ov = sv[tid + w];
            const int   oi = si[tid + w];
            if (ov > sv[tid] || (ov == sv[tid] && oi < si[tid])) {
                sv[tid] = ov;
                si[tid] = oi;
            }
        }
        __syncthreads();
    }
    if (tid == 0 && sv[0] > -FLT_MAX) {
        // pack: high 32 = float bits (nonneg => order-monotone),
        // low 32 = ~index => among equal values, larger ~index = smaller index
        const unsigned int fbits = __float_as_uint(sv[0]);
        const unsigned long long p =
            ((unsigned long long)fbits << 32) |
            (unsigned long long)(0xFFFFFFFFu - (unsigned int)si[0]);
        atomicMax(&packed[b], p);
    }
}

__global__ void finalize_kernel(
    int* __restrict__ out,
    const unsigned long long* __restrict__ packed,
    const int* __restrict__ flag, const int* __restrict__ writecol,
    int B, int L)
{
    const int b = blockIdx.x * blockDim.x + threadIdx.x;
    if (b >= B) return;
    if (!flag[b]) return;
    const unsigned long long p = packed[b];
    const int idx = (int)(0xFFFFFFFFu - (unsigned int)(p & 0xFFFFFFFFull));
    out[(size_t)b * (L + 1) + writecol[b]] = idx;
}

extern "C" void kernel_launch(void* const* d_in, const int* in_sizes, int n_in,
                              void* d_out, int out_size, void* d_ws, size_t ws_size,
                              hipStream_t stream) {
    const float* draft_probs   = (const float*)d_in[0];
    const float* target_probs  = (const float*)d_in[1];
    const float* uniform_probs = (const float*)d_in[2];
    const int*   draft_ids     = (const int*)d_in[3];
    const int*   cu            = (const int*)d_in[4];
    const int*   bonus         = (const int*)d_in[5];
    int*         out           = (int*)d_out;

    const int NT = in_sizes[2];
    const int V  = in_sizes[0] / NT;
    const int B  = in_sizes[4];
    const int L  = out_size / B - 1;

    unsigned long long* packed = (unsigned long long*)d_ws;
    int* flag     = (int*)((char*)d_ws + (size_t)B * 8);
    int* recrow   = (int*)((char*)d_ws + (size_t)B * 8 + (size_t)B * 4);
    int* writecol = (int*)((char*)d_ws + (size_t)B * 8 + (size_t)B * 8);

    const int bthreads = 256;
    const int bblocks  = (B + bthreads - 1) / bthreads;

    chain_kernel<<<bblocks, bthreads, 0, stream>>>(
        draft_probs, target_probs, uniform_probs, draft_ids, cu, bonus,
        out, packed, flag, recrow, writecol, B, V, NT, L);

    dim3 grid(B, SPLITS);
    argmax_partial_kernel<<<grid, 256, 0, stream>>>(
        target_probs, nullptr, packed, flag, recrow, V);

    finalize_kernel<<<bblocks, bthreads, 0, stream>>>(
        out, packed, flag, writecol, B, L);
}